// Round 15
// baseline (911.894 us; speedup 1.0000x reference)
//
#include <hip/hip_runtime.h>
#include <hip/hip_bf16.h>
#include <stdint.h>

#define D_MODEL 1024
#define D_FF    4096
#define N_EXP   8
#define TOPK    2
#define NTOK    8192
#define NASSIGN (NTOK*TOPK)

#define BM 128
#define BN 128
#define BK 64
#define THREADS 256
#define PGRID 768          // persistent grid: 3 blocks/CU x 256 CU

typedef __bf16 bf16_t;
typedef __attribute__((ext_vector_type(8))) bf16_t bf16x8;
typedef __attribute__((ext_vector_type(4))) float f32x4;
typedef __attribute__((ext_vector_type(8))) unsigned short u16x8;

__device__ __forceinline__ unsigned short f2bf(float f) {
    bf16_t b = (bf16_t)f;
    return __builtin_bit_cast(unsigned short, b);
}

__device__ __forceinline__ void gload_lds16(const void* g, void* l) {
    __builtin_amdgcn_global_load_lds(
        (const __attribute__((address_space(1))) void*)g,
        (__attribute__((address_space(3))) void*)l, 16, 0, 0);
}

// ---------------- fp32 -> bf16 convert: W1 and W2, 8 floats/thread/iter ----------------
__global__ void cvt_both_kernel(const float* __restrict__ W1, unsigned short* __restrict__ o1, long n1,
                                const float* __restrict__ W2, unsigned short* __restrict__ o2, long n2) {
    long stride = (long)gridDim.x * blockDim.x;
    long q1 = n1 / 8, q2 = n2 / 8;
    for (long i = (long)blockIdx.x * blockDim.x + threadIdx.x; i < q1 + q2; i += stride) {
        const float4* src; ushort4* dst; long k;
        if (i < q1) { src = (const float4*)W1; dst = (ushort4*)o1; k = i; }
        else        { src = (const float4*)W2; dst = (ushort4*)o2; k = i - q1; }
        float4 v0 = src[2 * k];
        float4 v1 = src[2 * k + 1];
        ushort4 a, b;
        a.x = f2bf(v0.x); a.y = f2bf(v0.y); a.z = f2bf(v0.z); a.w = f2bf(v0.w);
        b.x = f2bf(v1.x); b.y = f2bf(v1.y); b.z = f2bf(v1.z); b.w = f2bf(v1.w);
        dst[2 * k] = a;
        dst[2 * k + 1] = b;
    }
}

// ---------------- router (fused: also emits x in bf16) ----------------
__global__ __launch_bounds__(64) void router_kernel(
        const float* __restrict__ x, const float* __restrict__ gw,
        int* __restrict__ counts, int* __restrict__ ltok, float* __restrict__ lw,
        unsigned short* __restrict__ xb) {
    int n = blockIdx.x;
    int lane = threadIdx.x;
    const float* xr = x + (size_t)n * D_MODEL;
    unsigned short* xbr = xb + (size_t)n * D_MODEL;
    float acc[N_EXP];
    #pragma unroll
    for (int e = 0; e < N_EXP; e++) acc[e] = 0.f;
    #pragma unroll
    for (int i = 0; i < 4; i++) {
        int j = lane + i * 64;                  // float4 index
        float4 v = ((const float4*)xr)[j];
        ushort4 o;
        o.x = f2bf(v.x); o.y = f2bf(v.y); o.z = f2bf(v.z); o.w = f2bf(v.w);
        ((ushort4*)xbr)[j] = o;
        int d = j * 4;
        #pragma unroll
        for (int e = 0; e < N_EXP; e++) {
            const float* g = gw + e * D_MODEL + d;
            acc[e] += v.x * g[0] + v.y * g[1] + v.z * g[2] + v.w * g[3];
        }
    }
    #pragma unroll
    for (int e = 0; e < N_EXP; e++) {
        #pragma unroll
        for (int off = 32; off > 0; off >>= 1)
            acc[e] += __shfl_down(acc[e], off);
    }
    if (lane == 0) {
        float mx = acc[0];
        #pragma unroll
        for (int e = 1; e < N_EXP; e++) mx = fmaxf(mx, acc[e]);
        float p[N_EXP];
        float s = 0.f;
        #pragma unroll
        for (int e = 0; e < N_EXP; e++) { p[e] = expf(acc[e] - mx); s += p[e]; }
        float inv = 1.f / s;
        #pragma unroll
        for (int e = 0; e < N_EXP; e++) p[e] *= inv;
        int i0 = 0;
        #pragma unroll
        for (int e = 1; e < N_EXP; e++) if (p[e] > p[i0]) i0 = e;
        int i1 = (i0 == 0) ? 1 : 0;
        #pragma unroll
        for (int e = 0; e < N_EXP; e++) if (e != i0 && p[e] > p[i1]) i1 = e;
        float s2 = p[i0] + p[i1] + 1e-9f;
        float w0 = p[i0] / s2, w1 = p[i1] / s2;
        int pos0 = atomicAdd(&counts[i0], 1);
        ltok[i0 * NTOK + pos0] = n; lw[i0 * NTOK + pos0] = w0;
        int pos1 = atomicAdd(&counts[i1], 1);
        ltok[i1 * NTOK + pos1] = n; lw[i1 * NTOK + pos1] = w1;
    }
}

// ---------------- exclusive scan over 8 expert counts ----------------
__global__ void scan_kernel(const int* __restrict__ counts, int* __restrict__ offs) {
    if (threadIdx.x == 0 && blockIdx.x == 0) {
        int s = 0;
        for (int e = 0; e < N_EXP; e++) { offs[e] = s; s += counts[e]; }
    }
}

// =====================================================================
// r15 = r14 + PERSISTENT GRIDS (768 blocks = exactly 3/CU): gemm2's
// 1024 active tiles previously ran as a full 3/CU round + a 256-block
// tail round at 1/CU (no m114 overlap; ~40% of wall time). Tile-stride
// loop keeps every round at 3/CU; stride 768 % 8 == 0 preserves the
// expert->XCD mapping and panel-major order. Bodies byte-identical r14.
// =====================================================================

// GEMM1: h = relu(X_gathered @ W1[e]^T + b1[e])
__global__ __launch_bounds__(THREADS, 3) void gemm1_kernel(
        const unsigned short* __restrict__ xb, const unsigned short* __restrict__ w1b,
        const float* __restrict__ b1,
        const int* __restrict__ counts, const int* __restrict__ offs,
        const int* __restrict__ ltok,
        unsigned short* __restrict__ hb) {
    const int NTM = NTOK / BM;   // 64 (worst case)
    const int NTILES = N_EXP * NTM * (D_FF / BN);
    int t = threadIdx.x;
    int lane = t & 63, w = t >> 6;     // 4 waves
    int wr = w >> 1, wc = w & 1;       // 2 x 2
    int srow = t >> 3;                 // 0..31
    int schunk = (t & 7) ^ (srow & 7);

    __shared__ __align__(16) unsigned short As[BM * BK];   // 16 KB
    __shared__ __align__(16) unsigned short Bs[BN * BK];   // 16 KB
    char* As_b = (char*)As;
    char* Bs_b = (char*)Bs;

    int arow_base = wr * 64 + (lane & 15);
    int brow_base = wc * 64 + (lane & 15);
    int ch[2];
    #pragma unroll
    for (int ks = 0; ks < 2; ks++)
        ch[ks] = ((ks * 4 + (lane >> 4)) ^ (lane & 7)) << 4;

    for (int b = blockIdx.x; b < NTILES; b += PGRID) {
        int e = b & 7;               // expert -> XCD (stride 768 preserves)
        int idx = b >> 3;
        int nt = idx / NTM;          // W-panel major
        int mt = idx % NTM;
        int cnt = counts[e];
        if (mt * BM >= cnt) continue;

        const unsigned short* aptr[4];
        const unsigned short* bptr[4];
        #pragma unroll
        for (int j = 0; j < 4; j++) {
            int rr = srow + j * 32;
            int slot = mt * BM + rr;
            int cs = slot < cnt ? slot : (cnt - 1);
            int tok = ltok[e * NTOK + cs];
            aptr[j] = xb + (size_t)tok * D_MODEL + schunk * 8;
            bptr[j] = w1b + ((size_t)e * D_FF + nt * BN + rr) * D_MODEL + schunk * 8;
        }

        f32x4 acc[4][4];
        #pragma unroll
        for (int m = 0; m < 4; m++)
            #pragma unroll
            for (int n = 0; n < 4; n++)
                acc[m][n] = (f32x4){0.f, 0.f, 0.f, 0.f};

        for (int k0 = 0; k0 < D_MODEL; k0 += BK) {
            #pragma unroll
            for (int j = 0; j < 4; j++) {
                gload_lds16(aptr[j] + k0, As_b + j * 4096 + t * 16);
                gload_lds16(bptr[j] + k0, Bs_b + j * 4096 + t * 16);
            }
            __syncthreads();
            bf16x8 af[2][4], bf[2][4];
            #pragma unroll
            for (int ks = 0; ks < 2; ks++) {
                #pragma unroll
                for (int m = 0; m < 4; m++)
                    af[ks][m] = *(const bf16x8*)(As_b + (size_t)(arow_base + m * 16) * 128 + ch[ks]);
                #pragma unroll
                for (int n = 0; n < 4; n++)
                    bf[ks][n] = *(const bf16x8*)(Bs_b + (size_t)(brow_base + n * 16) * 128 + ch[ks]);
            }
            #pragma unroll
            for (int ks = 0; ks < 2; ks++)
                #pragma unroll
                for (int m = 0; m < 4; m++)
                    #pragma unroll
                    for (int n = 0; n < 4; n++)
                        acc[m][n] = __builtin_amdgcn_mfma_f32_16x16x32_bf16(af[ks][m], bf[ks][n], acc[m][n], 0, 0, 0);
            __syncthreads();
        }

        // epilogue: relu+bias, per-wave LDS repack, coalesced ushort8 stores
        int hbase = offs[e];
        float biasv[4];
        #pragma unroll
        for (int n = 0; n < 4; ++n)
            biasv[n] = b1[e * D_FF + nt * BN + wc * 64 + n * 16 + (lane & 15)];
        unsigned short* Hs = (unsigned short*)(As_b) + w * 1216;
        #pragma unroll
        for (int m = 0; m < 4; ++m) {
            #pragma unroll
            for (int n = 0; n < 4; ++n) {
                #pragma unroll
                for (int rq = 0; rq < 4; ++rq) {
                    int lr = (lane >> 4) * 4 + rq;      // 0..15
                    int lc = n * 16 + (lane & 15);      // 0..63
                    float v = fmaxf(acc[m][n][rq] + biasv[n], 0.f);
                    Hs[lr * 72 + lc] = f2bf(v);
                }
            }
            #pragma unroll
            for (int half = 0; half < 2; ++half) {
                int lr = half * 8 + (lane >> 3);        // 0..15
                u16x8 vv = *(const u16x8*)(Hs + lr * 72 + (lane & 7) * 8);
                int s = mt * BM + wr * 64 + m * 16 + lr;
                if (s < cnt) {
                    *(u16x8*)(hb + (size_t)(hbase + s) * D_FF + nt * BN + wc * 64 + (lane & 7) * 8) = vv;
                }
            }
        }
        __syncthreads();   // LDS (As/Hs) safe for next persistent tile
    }
}

// GEMM2: y = h @ W2[e]^T + b2[e]; weighted atomic scatter to out
__global__ __launch_bounds__(THREADS, 3) void gemm2_kernel(
        const unsigned short* __restrict__ hb, const unsigned short* __restrict__ w2b,
        const float* __restrict__ b2,
        const int* __restrict__ counts, const int* __restrict__ offs,
        const int* __restrict__ ltok, const float* __restrict__ lw,
        float* __restrict__ out) {
    const int NTM = NTOK / BM;     // 64
    const int NTILES = N_EXP * NTM * (D_MODEL / BN);
    int t = threadIdx.x;
    int lane = t & 63, w = t >> 6;
    int wr = w >> 1, wc = w & 1;
    int srow = t >> 3;
    int schunk = (t & 7) ^ (srow & 7);

    __shared__ __align__(16) unsigned short As[BM * BK];
    __shared__ __align__(16) unsigned short Bs[BN * BK];
    char* As_b = (char*)As;
    char* Bs_b = (char*)Bs;

    int arow_base = wr * 64 + (lane & 15);
    int brow_base = wc * 64 + (lane & 15);
    int ch[2];
    #pragma unroll
    for (int ks = 0; ks < 2; ks++)
        ch[ks] = ((ks * 4 + (lane >> 4)) ^ (lane & 7)) << 4;

    for (int b = blockIdx.x; b < NTILES; b += PGRID) {
        int e = b & 7;
        int idx = b >> 3;
        int nt = idx / NTM;
        int mt = idx % NTM;
        int cnt = counts[e];
        if (mt * BM >= cnt) continue;
        int hbase = offs[e];

        const unsigned short* aptr[4];
        const unsigned short* bptr[4];
        #pragma unroll
        for (int j = 0; j < 4; j++) {
            int rr = srow + j * 32;
            int slot = mt * BM + rr;
            int cs = slot < cnt ? slot : (cnt - 1);
            aptr[j] = hb + (size_t)(hbase + cs) * D_FF + schunk * 8;
            bptr[j] = w2b + ((size_t)e * D_MODEL + nt * BN + rr) * D_FF + schunk * 8;
        }

        f32x4 acc[4][4];
        #pragma unroll
        for (int m = 0; m < 4; m++)
            #pragma unroll
            for (int n = 0; n < 4; n++)
                acc[m][n] = (f32x4){0.f, 0.f, 0.f, 0.f};

        for (int k0 = 0; k0 < D_FF; k0 += BK) {
            #pragma unroll
            for (int j = 0; j < 4; j++) {
                gload_lds16(aptr[j] + k0, As_b + j * 4096 + t * 16);
                gload_lds16(bptr[j] + k0, Bs_b + j * 4096 + t * 16);
            }
            __syncthreads();
            bf16x8 af[2][4], bf[2][4];
            #pragma unroll
            for (int ks = 0; ks < 2; ks++) {
                #pragma unroll
                for (int m = 0; m < 4; m++)
                    af[ks][m] = *(const bf16x8*)(As_b + (size_t)(arow_base + m * 16) * 128 + ch[ks]);
                #pragma unroll
                for (int n = 0; n < 4; n++)
                    bf[ks][n] = *(const bf16x8*)(Bs_b + (size_t)(brow_base + n * 16) * 128 + ch[ks]);
            }
            #pragma unroll
            for (int ks = 0; ks < 2; ks++)
                #pragma unroll
                for (int m = 0; m < 4; m++)
                    #pragma unroll
                    for (int n = 0; n < 4; n++)
                        acc[m][n] = __builtin_amdgcn_mfma_f32_16x16x32_bf16(af[ks][m], bf[ks][n], acc[m][n], 0, 0, 0);
            __syncthreads();
        }

        int lbase = e * NTOK;
        float biasv[4];
        #pragma unroll
        for (int n = 0; n < 4; ++n)
            biasv[n] = b2[e * D_MODEL + nt * BN + wc * 64 + n * 16 + (lane & 15)];
        #pragma unroll
        for (int m = 0; m < 4; ++m) {
            int s0 = mt * BM + wr * 64 + m * 16 + (lane >> 4) * 4;
            #pragma unroll
            for (int rq = 0; rq < 4; ++rq) {
                int s = s0 + rq;
                if (s >= cnt) continue;
                int tok = ltok[lbase + s];
                float wgt = lw[lbase + s];
                float* orow = out + (size_t)tok * D_MODEL + nt * BN + wc * 64 + (lane & 15);
                #pragma unroll
                for (int n = 0; n < 4; ++n)
                    atomicAdd(orow + n * 16, wgt * (acc[m][n][rq] + biasv[n]));
            }
        }
        __syncthreads();
    }
}

extern "C" void kernel_launch(void* const* d_in, const int* in_sizes, int n_in,
                              void* d_out, int out_size, void* d_ws, size_t ws_size,
                              hipStream_t stream) {
    const float* x  = (const float*)d_in[0];
    const float* gw = (const float*)d_in[1];
    const float* W1 = (const float*)d_in[2];
    const float* b1 = (const float*)d_in[3];
    const float* W2 = (const float*)d_in[4];
    const float* b2 = (const float*)d_in[5];
    float* out = (float*)d_out;

    char* ws = (char*)d_ws;
    size_t off = 0;
    auto alloc = [&](size_t bytes) -> char* {
        char* p = ws + off;
        off += (bytes + 255) & ~(size_t)255;
        return p;
    };
    unsigned short* xb  = (unsigned short*)alloc((size_t)NTOK * D_MODEL * 2);
    unsigned short* w1b = (unsigned short*)alloc((size_t)N_EXP * D_FF * D_MODEL * 2);
    unsigned short* w2b = (unsigned short*)alloc((size_t)N_EXP * D_MODEL * D_FF * 2);
    unsigned short* hb  = (unsigned short*)alloc((size_t)NASSIGN * D_FF * 2);
    int*   counts = (int*)alloc(256);
    int*   offs   = (int*)alloc(256);
    int*   ltok   = (int*)alloc((size_t)N_EXP * NTOK * 4);
    float* lw     = (float*)alloc((size_t)N_EXP * NTOK * 4);

    hipMemsetAsync(out, 0, (size_t)out_size * 4, stream);
    hipMemsetAsync(counts, 0, 256, stream);
    cvt_both_kernel<<<2048, 256, 0, stream>>>(
        W1, w1b, (long)N_EXP * D_FF * D_MODEL, W2, w2b, (long)N_EXP * D_MODEL * D_FF);
    router_kernel<<<NTOK, 64, 0, stream>>>(x, gw, counts, ltok, lw, xb);
    scan_kernel<<<1, 64, 0, stream>>>(counts, offs);
    gemm1_kernel<<<PGRID, THREADS, 0, stream>>>(
        xb, w1b, b1, counts, offs, ltok, hb);
    gemm2_kernel<<<PGRID, THREADS, 0, stream>>>(
        hb, w2b, b2, counts, offs, ltok, lw, out);
}

// Round 16
// 660.259 us; speedup vs baseline: 1.3811x; 1.3811x over previous
//
#include <hip/hip_runtime.h>
#include <hip/hip_bf16.h>
#include <stdint.h>

#define D_MODEL 1024
#define D_FF    4096
#define N_EXP   8
#define TOPK    2
#define NTOK    8192
#define NASSIGN (NTOK*TOPK)

#define BM 128
#define BN 128
#define BK 64
#define THREADS 256

typedef __bf16 bf16_t;
typedef __attribute__((ext_vector_type(8))) bf16_t bf16x8;
typedef __attribute__((ext_vector_type(4))) float f32x4;
typedef __attribute__((ext_vector_type(8))) unsigned short u16x8;

__device__ __forceinline__ unsigned short f2bf(float f) {
    bf16_t b = (bf16_t)f;
    return __builtin_bit_cast(unsigned short, b);
}

__device__ __forceinline__ void gload_lds16(const void* g, void* l) {
    __builtin_amdgcn_global_load_lds(
        (const __attribute__((address_space(1))) void*)g,
        (__attribute__((address_space(3))) void*)l, 16, 0, 0);
}

// ---------------- fp32 -> bf16 convert W1+W2; also zeroes counts ----------------
__global__ void cvt_both_kernel(const float* __restrict__ W1, unsigned short* __restrict__ o1, long n1,
                                const float* __restrict__ W2, unsigned short* __restrict__ o2, long n2,
                                int* __restrict__ counts) {
    if (blockIdx.x == 0 && threadIdx.x < N_EXP) counts[threadIdx.x] = 0;
    long stride = (long)gridDim.x * blockDim.x;
    long q1 = n1 / 8, q2 = n2 / 8;
    for (long i = (long)blockIdx.x * blockDim.x + threadIdx.x; i < q1 + q2; i += stride) {
        const float4* src; ushort4* dst; long k;
        if (i < q1) { src = (const float4*)W1; dst = (ushort4*)o1; k = i; }
        else        { src = (const float4*)W2; dst = (ushort4*)o2; k = i - q1; }
        float4 v0 = src[2 * k];
        float4 v1 = src[2 * k + 1];
        ushort4 a, b;
        a.x = f2bf(v0.x); a.y = f2bf(v0.y); a.z = f2bf(v0.z); a.w = f2bf(v0.w);
        b.x = f2bf(v1.x); b.y = f2bf(v1.y); b.z = f2bf(v1.z); b.w = f2bf(v1.w);
        dst[2 * k] = a;
        dst[2 * k + 1] = b;
    }
}

// ---------------- router (fused: emits x bf16, zeroes its out row) ----------------
__global__ __launch_bounds__(64) void router_kernel(
        const float* __restrict__ x, const float* __restrict__ gw,
        int* __restrict__ counts, int* __restrict__ ltok, float* __restrict__ lw,
        unsigned short* __restrict__ xb, float* __restrict__ out) {
    int n = blockIdx.x;
    int lane = threadIdx.x;
    const float* xr = x + (size_t)n * D_MODEL;
    unsigned short* xbr = xb + (size_t)n * D_MODEL;
    // zero this token's output row (replaces the 32MB memset launch;
    // runs before gemm2's atomics by stream order)
    float4 z = make_float4(0.f, 0.f, 0.f, 0.f);
    float4* orow4 = (float4*)(out + (size_t)n * D_MODEL);
    #pragma unroll
    for (int i = 0; i < 4; i++) orow4[lane + i * 64] = z;

    float acc[N_EXP];
    #pragma unroll
    for (int e = 0; e < N_EXP; e++) acc[e] = 0.f;
    #pragma unroll
    for (int i = 0; i < 4; i++) {
        int j = lane + i * 64;                  // float4 index
        float4 v = ((const float4*)xr)[j];
        ushort4 o;
        o.x = f2bf(v.x); o.y = f2bf(v.y); o.z = f2bf(v.z); o.w = f2bf(v.w);
        ((ushort4*)xbr)[j] = o;
        int d = j * 4;
        #pragma unroll
        for (int e = 0; e < N_EXP; e++) {
            const float* g = gw + e * D_MODEL + d;
            acc[e] += v.x * g[0] + v.y * g[1] + v.z * g[2] + v.w * g[3];
        }
    }
    #pragma unroll
    for (int e = 0; e < N_EXP; e++) {
        #pragma unroll
        for (int off = 32; off > 0; off >>= 1)
            acc[e] += __shfl_down(acc[e], off);
    }
    if (lane == 0) {
        float mx = acc[0];
        #pragma unroll
        for (int e = 1; e < N_EXP; e++) mx = fmaxf(mx, acc[e]);
        float p[N_EXP];
        float s = 0.f;
        #pragma unroll
        for (int e = 0; e < N_EXP; e++) { p[e] = expf(acc[e] - mx); s += p[e]; }
        float inv = 1.f / s;
        #pragma unroll
        for (int e = 0; e < N_EXP; e++) p[e] *= inv;
        int i0 = 0;
        #pragma unroll
        for (int e = 1; e < N_EXP; e++) if (p[e] > p[i0]) i0 = e;
        int i1 = (i0 == 0) ? 1 : 0;
        #pragma unroll
        for (int e = 0; e < N_EXP; e++) if (e != i0 && p[e] > p[i1]) i1 = e;
        float s2 = p[i0] + p[i1] + 1e-9f;
        float w0 = p[i0] / s2, w1 = p[i1] / s2;
        int pos0 = atomicAdd(&counts[i0], 1);
        ltok[i0 * NTOK + pos0] = n; lw[i0 * NTOK + pos0] = w0;
        int pos1 = atomicAdd(&counts[i1], 1);
        ltok[i1 * NTOK + pos1] = n; lw[i1 * NTOK + pos1] = w1;
    }
}

// ---------------- exclusive scan over 8 expert counts ----------------
__global__ void scan_kernel(const int* __restrict__ counts, int* __restrict__ offs) {
    if (threadIdx.x == 0 && blockIdx.x == 0) {
        int s = 0;
        for (int e = 0; e < N_EXP; e++) { offs[e] = s; s += counts[e]; }
    }
}

// =====================================================================
// r16 = r14 verbatim GEMMs (measured best, 674us total; gemm2 225us
// FETCH~ideal conflicts=0). Persistent-grid r15 falsified (-35%: stride
// walk destroyed XCD panel locality, FETCH 218->400MB). This round only
// trims fixed costs: memset launches folded into cvt (counts) and
// router (out rows). 5 launches total.
// =====================================================================

// GEMM1: h = relu(X_gathered @ W1[e]^T + b1[e])
__global__ __launch_bounds__(THREADS, 3) void gemm1_kernel(
        const unsigned short* __restrict__ xb, const unsigned short* __restrict__ w1b,
        const float* __restrict__ b1,
        const int* __restrict__ counts, const int* __restrict__ offs,
        const int* __restrict__ ltok,
        unsigned short* __restrict__ hb) {
    const int NTM = NTOK / BM;   // 64 (worst case)
    int b = blockIdx.x;
    int e = b & 7;               // expert -> XCD
    int idx = b >> 3;
    int nt = idx / NTM;          // W-panel major: co-resident blocks share nt
    int mt = idx % NTM;
    int cnt = counts[e];
    if (mt * BM >= cnt) return;

    __shared__ __align__(16) unsigned short As[BM * BK];   // 16 KB
    __shared__ __align__(16) unsigned short Bs[BN * BK];   // 16 KB

    int t = threadIdx.x;
    int lane = t & 63, w = t >> 6;     // 4 waves
    int wr = w >> 1, wc = w & 1;       // 2 x 2

    int srow = t >> 3;                       // 0..31
    int schunk = (t & 7) ^ (srow & 7);
    const unsigned short* aptr[4];
    const unsigned short* bptr[4];
    #pragma unroll
    for (int j = 0; j < 4; j++) {
        int rr = srow + j * 32;
        int slot = mt * BM + rr;
        int cs = slot < cnt ? slot : (cnt - 1);
        int tok = ltok[e * NTOK + cs];
        aptr[j] = xb + (size_t)tok * D_MODEL + schunk * 8;
        bptr[j] = w1b + ((size_t)e * D_FF + nt * BN + rr) * D_MODEL + schunk * 8;
    }
    char* As_b = (char*)As;
    char* Bs_b = (char*)Bs;

    int arow_base = wr * 64 + (lane & 15);
    int brow_base = wc * 64 + (lane & 15);
    int ch[2];
    #pragma unroll
    for (int ks = 0; ks < 2; ks++)
        ch[ks] = ((ks * 4 + (lane >> 4)) ^ (lane & 7)) << 4;

    f32x4 acc[4][4];
    #pragma unroll
    for (int m = 0; m < 4; m++)
        #pragma unroll
        for (int n = 0; n < 4; n++)
            acc[m][n] = (f32x4){0.f, 0.f, 0.f, 0.f};

    for (int k0 = 0; k0 < D_MODEL; k0 += BK) {
        #pragma unroll
        for (int j = 0; j < 4; j++) {
            gload_lds16(aptr[j] + k0, As_b + j * 4096 + t * 16);
            gload_lds16(bptr[j] + k0, Bs_b + j * 4096 + t * 16);
        }
        __syncthreads();
        bf16x8 af[2][4], bf[2][4];
        #pragma unroll
        for (int ks = 0; ks < 2; ks++) {
            #pragma unroll
            for (int m = 0; m < 4; m++)
                af[ks][m] = *(const bf16x8*)(As_b + (size_t)(arow_base + m * 16) * 128 + ch[ks]);
            #pragma unroll
            for (int n = 0; n < 4; n++)
                bf[ks][n] = *(const bf16x8*)(Bs_b + (size_t)(brow_base + n * 16) * 128 + ch[ks]);
        }
        #pragma unroll
        for (int ks = 0; ks < 2; ks++)
            #pragma unroll
            for (int m = 0; m < 4; m++)
                #pragma unroll
                for (int n = 0; n < 4; n++)
                    acc[m][n] = __builtin_amdgcn_mfma_f32_16x16x32_bf16(af[ks][m], bf[ks][n], acc[m][n], 0, 0, 0);
        __syncthreads();
    }

    // ---- epilogue: relu+bias, per-wave LDS repack, coalesced ushort8 stores
    int hbase = offs[e];
    float biasv[4];
    #pragma unroll
    for (int n = 0; n < 4; ++n)
        biasv[n] = b1[e * D_FF + nt * BN + wc * 64 + n * 16 + (lane & 15)];
    unsigned short* Hs = (unsigned short*)(As_b) + w * 1216;
    #pragma unroll
    for (int m = 0; m < 4; ++m) {
        #pragma unroll
        for (int n = 0; n < 4; ++n) {
            #pragma unroll
            for (int rq = 0; rq < 4; ++rq) {
                int lr = (lane >> 4) * 4 + rq;      // 0..15
                int lc = n * 16 + (lane & 15);      // 0..63
                float v = fmaxf(acc[m][n][rq] + biasv[n], 0.f);
                Hs[lr * 72 + lc] = f2bf(v);
            }
        }
        #pragma unroll
        for (int half = 0; half < 2; ++half) {
            int lr = half * 8 + (lane >> 3);        // 0..15
            u16x8 vv = *(const u16x8*)(Hs + lr * 72 + (lane & 7) * 8);
            int s = mt * BM + wr * 64 + m * 16 + lr;
            if (s < cnt) {
                *(u16x8*)(hb + (size_t)(hbase + s) * D_FF + nt * BN + wc * 64 + (lane & 7) * 8) = vv;
            }
        }
    }
}

// GEMM2: y = h @ W2[e]^T + b2[e]; weighted atomic scatter to out
__global__ __launch_bounds__(THREADS, 3) void gemm2_kernel(
        const unsigned short* __restrict__ hb, const unsigned short* __restrict__ w2b,
        const float* __restrict__ b2,
        const int* __restrict__ counts, const int* __restrict__ offs,
        const int* __restrict__ ltok, const float* __restrict__ lw,
        float* __restrict__ out) {
    const int NTM = NTOK / BM;     // 64
    int b = blockIdx.x;
    int e = b & 7;
    int idx = b >> 3;
    int nt = idx / NTM;
    int mt = idx % NTM;
    int cnt = counts[e];
    if (mt * BM >= cnt) return;
    int hbase = offs[e];

    __shared__ __align__(16) unsigned short As[BM * BK];
    __shared__ __align__(16) unsigned short Bs[BN * BK];

    int t = threadIdx.x;
    int lane = t & 63, w = t >> 6;
    int wr = w >> 1, wc = w & 1;

    int srow = t >> 3;
    int schunk = (t & 7) ^ (srow & 7);
    const unsigned short* aptr[4];
    const unsigned short* bptr[4];
    #pragma unroll
    for (int j = 0; j < 4; j++) {
        int rr = srow + j * 32;
        int slot = mt * BM + rr;
        int cs = slot < cnt ? slot : (cnt - 1);
        aptr[j] = hb + (size_t)(hbase + cs) * D_FF + schunk * 8;
        bptr[j] = w2b + ((size_t)e * D_MODEL + nt * BN + rr) * D_FF + schunk * 8;
    }
    char* As_b = (char*)As;
    char* Bs_b = (char*)Bs;

    int arow_base = wr * 64 + (lane & 15);
    int brow_base = wc * 64 + (lane & 15);
    int ch[2];
    #pragma unroll
    for (int ks = 0; ks < 2; ks++)
        ch[ks] = ((ks * 4 + (lane >> 4)) ^ (lane & 7)) << 4;

    f32x4 acc[4][4];
    #pragma unroll
    for (int m = 0; m < 4; m++)
        #pragma unroll
        for (int n = 0; n < 4; n++)
            acc[m][n] = (f32x4){0.f, 0.f, 0.f, 0.f};

    for (int k0 = 0; k0 < D_FF; k0 += BK) {
        #pragma unroll
        for (int j = 0; j < 4; j++) {
            gload_lds16(aptr[j] + k0, As_b + j * 4096 + t * 16);
            gload_lds16(bptr[j] + k0, Bs_b + j * 4096 + t * 16);
        }
        __syncthreads();
        bf16x8 af[2][4], bf[2][4];
        #pragma unroll
        for (int ks = 0; ks < 2; ks++) {
            #pragma unroll
            for (int m = 0; m < 4; m++)
                af[ks][m] = *(const bf16x8*)(As_b + (size_t)(arow_base + m * 16) * 128 + ch[ks]);
            #pragma unroll
            for (int n = 0; n < 4; n++)
                bf[ks][n] = *(const bf16x8*)(Bs_b + (size_t)(brow_base + n * 16) * 128 + ch[ks]);
        }
        #pragma unroll
        for (int ks = 0; ks < 2; ks++)
            #pragma unroll
            for (int m = 0; m < 4; m++)
                #pragma unroll
                for (int n = 0; n < 4; n++)
                    acc[m][n] = __builtin_amdgcn_mfma_f32_16x16x32_bf16(af[ks][m], bf[ks][n], acc[m][n], 0, 0, 0);
        __syncthreads();
    }

    int lbase = e * NTOK;
    float biasv[4];
    #pragma unroll
    for (int n = 0; n < 4; ++n)
        biasv[n] = b2[e * D_MODEL + nt * BN + wc * 64 + n * 16 + (lane & 15)];
    #pragma unroll
    for (int m = 0; m < 4; ++m) {
        int s0 = mt * BM + wr * 64 + m * 16 + (lane >> 4) * 4;
        #pragma unroll
        for (int rq = 0; rq < 4; ++rq) {
            int s = s0 + rq;
            if (s >= cnt) continue;
            int tok = ltok[lbase + s];
            float wgt = lw[lbase + s];
            float* orow = out + (size_t)tok * D_MODEL + nt * BN + wc * 64 + (lane & 15);
            #pragma unroll
            for (int n = 0; n < 4; ++n)
                atomicAdd(orow + n * 16, wgt * (acc[m][n][rq] + biasv[n]));
        }
    }
}

extern "C" void kernel_launch(void* const* d_in, const int* in_sizes, int n_in,
                              void* d_out, int out_size, void* d_ws, size_t ws_size,
                              hipStream_t stream) {
    const float* x  = (const float*)d_in[0];
    const float* gw = (const float*)d_in[1];
    const float* W1 = (const float*)d_in[2];
    const float* b1 = (const float*)d_in[3];
    const float* W2 = (const float*)d_in[4];
    const float* b2 = (const float*)d_in[5];
    float* out = (float*)d_out;

    char* ws = (char*)d_ws;
    size_t off = 0;
    auto alloc = [&](size_t bytes) -> char* {
        char* p = ws + off;
        off += (bytes + 255) & ~(size_t)255;
        return p;
    };
    unsigned short* xb  = (unsigned short*)alloc((size_t)NTOK * D_MODEL * 2);
    unsigned short* w1b = (unsigned short*)alloc((size_t)N_EXP * D_FF * D_MODEL * 2);
    unsigned short* w2b = (unsigned short*)alloc((size_t)N_EXP * D_MODEL * D_FF * 2);
    unsigned short* hb  = (unsigned short*)alloc((size_t)NASSIGN * D_FF * 2);
    int*   counts = (int*)alloc(256);
    int*   offs   = (int*)alloc(256);
    int*   ltok   = (int*)alloc((size_t)N_EXP * NTOK * 4);
    float* lw     = (float*)alloc((size_t)N_EXP * NTOK * 4);

    cvt_both_kernel<<<2048, 256, 0, stream>>>(
        W1, w1b, (long)N_EXP * D_FF * D_MODEL, W2, w2b, (long)N_EXP * D_MODEL * D_FF, counts);
    router_kernel<<<NTOK, 64, 0, stream>>>(x, gw, counts, ltok, lw, xb, out);
    scan_kernel<<<1, 64, 0, stream>>>(counts, offs);
    gemm1_kernel<<<N_EXP * (NTOK / BM) * (D_FF / BN), THREADS, 0, stream>>>(
        xb, w1b, b1, counts, offs, ltok, hb);
    gemm2_kernel<<<N_EXP * (NTOK / BM) * (D_MODEL / BN), THREADS, 0, stream>>>(
        hb, w2b, b2, counts, offs, ltok, lw, out);
}

// Round 17
// 654.387 us; speedup vs baseline: 1.3935x; 1.0090x over previous
//
#include <hip/hip_runtime.h>
#include <hip/hip_bf16.h>
#include <stdint.h>

#define D_MODEL 1024
#define D_FF    4096
#define N_EXP   8
#define TOPK    2
#define NTOK    8192
#define NASSIGN (NTOK*TOPK)

#define BM 128
#define BN 128
#define BK 64
#define THREADS 256

typedef __bf16 bf16_t;
typedef __attribute__((ext_vector_type(8))) bf16_t bf16x8;
typedef __attribute__((ext_vector_type(4))) float f32x4;
typedef __attribute__((ext_vector_type(8))) unsigned short u16x8;

__device__ __forceinline__ unsigned short f2bf(float f) {
    bf16_t b = (bf16_t)f;
    return __builtin_bit_cast(unsigned short, b);
}

__device__ __forceinline__ void gload_lds16(const void* g, void* l) {
    __builtin_amdgcn_global_load_lds(
        (const __attribute__((address_space(1))) void*)g,
        (__attribute__((address_space(3))) void*)l, 16, 0, 0);
}

// =====================================================================
// r17: fuse cvt (BW-bound) + router (latency-bound) into ONE dispatch so
// they overlap instead of serializing (130us -> ~95 predicted).
// Blocks 0..2047: router, 4 waves = 4 tokens each (pure wave-level code).
// Blocks 2048..4095: W1/W2 fp32->bf16 grid-stride.
// GEMMs byte-identical to r16 (measured floor: gemm2 225us, FETCH~ideal,
// conflicts 0, the r12/r14/r16 fingerprint).
// =====================================================================
__global__ __launch_bounds__(256) void fused_pre_kernel(
        const float* __restrict__ x, const float* __restrict__ gw,
        int* __restrict__ counts, int* __restrict__ ltok, float* __restrict__ lw,
        unsigned short* __restrict__ xb, float* __restrict__ out,
        const float* __restrict__ W1, unsigned short* __restrict__ o1, long n1,
        const float* __restrict__ W2, unsigned short* __restrict__ o2, long n2) {
    int blk = blockIdx.x;
    if (blk < 2048) {
        // ---------------- router: wave w -> token blk*4+w ----------------
        int w = threadIdx.x >> 6;
        int lane = threadIdx.x & 63;
        int n = blk * 4 + w;
        const float* xr = x + (size_t)n * D_MODEL;
        unsigned short* xbr = xb + (size_t)n * D_MODEL;
        // zero this token's output row (replaces 32MB memset launch)
        float4 z = make_float4(0.f, 0.f, 0.f, 0.f);
        float4* orow4 = (float4*)(out + (size_t)n * D_MODEL);
        #pragma unroll
        for (int i = 0; i < 4; i++) orow4[lane + i * 64] = z;

        float acc[N_EXP];
        #pragma unroll
        for (int e = 0; e < N_EXP; e++) acc[e] = 0.f;
        #pragma unroll
        for (int i = 0; i < 4; i++) {
            int j = lane + i * 64;                  // float4 index
            float4 v = ((const float4*)xr)[j];
            ushort4 o;
            o.x = f2bf(v.x); o.y = f2bf(v.y); o.z = f2bf(v.z); o.w = f2bf(v.w);
            ((ushort4*)xbr)[j] = o;
            int d = j * 4;
            #pragma unroll
            for (int e = 0; e < N_EXP; e++) {
                const float* g = gw + e * D_MODEL + d;
                acc[e] += v.x * g[0] + v.y * g[1] + v.z * g[2] + v.w * g[3];
            }
        }
        #pragma unroll
        for (int e = 0; e < N_EXP; e++) {
            #pragma unroll
            for (int off = 32; off > 0; off >>= 1)
                acc[e] += __shfl_down(acc[e], off);
        }
        if (lane == 0) {
            float mx = acc[0];
            #pragma unroll
            for (int e = 1; e < N_EXP; e++) mx = fmaxf(mx, acc[e]);
            float p[N_EXP];
            float s = 0.f;
            #pragma unroll
            for (int e = 0; e < N_EXP; e++) { p[e] = expf(acc[e] - mx); s += p[e]; }
            float inv = 1.f / s;
            #pragma unroll
            for (int e = 0; e < N_EXP; e++) p[e] *= inv;
            int i0 = 0;
            #pragma unroll
            for (int e = 1; e < N_EXP; e++) if (p[e] > p[i0]) i0 = e;
            int i1 = (i0 == 0) ? 1 : 0;
            #pragma unroll
            for (int e = 0; e < N_EXP; e++) if (e != i0 && p[e] > p[i1]) i1 = e;
            float s2 = p[i0] + p[i1] + 1e-9f;
            float w0 = p[i0] / s2, w1 = p[i1] / s2;
            int pos0 = atomicAdd(&counts[i0], 1);
            ltok[i0 * NTOK + pos0] = n; lw[i0 * NTOK + pos0] = w0;
            int pos1 = atomicAdd(&counts[i1], 1);
            ltok[i1 * NTOK + pos1] = n; lw[i1 * NTOK + pos1] = w1;
        }
    } else {
        // ---------------- weight cvt: fp32 -> bf16, 8 floats/thread/iter ----------------
        long stride = 2048L * 256;
        long q1 = n1 / 8, q2 = n2 / 8;
        for (long i = (long)(blk - 2048) * 256 + threadIdx.x; i < q1 + q2; i += stride) {
            const float4* src; ushort4* dst; long k;
            if (i < q1) { src = (const float4*)W1; dst = (ushort4*)o1; k = i; }
            else        { src = (const float4*)W2; dst = (ushort4*)o2; k = i - q1; }
            float4 v0 = src[2 * k];
            float4 v1 = src[2 * k + 1];
            ushort4 a, b;
            a.x = f2bf(v0.x); a.y = f2bf(v0.y); a.z = f2bf(v0.z); a.w = f2bf(v0.w);
            b.x = f2bf(v1.x); b.y = f2bf(v1.y); b.z = f2bf(v1.z); b.w = f2bf(v1.w);
            dst[2 * k] = a;
            dst[2 * k + 1] = b;
        }
    }
}

// ---------------- exclusive scan over 8 expert counts ----------------
__global__ void scan_kernel(const int* __restrict__ counts, int* __restrict__ offs) {
    if (threadIdx.x == 0 && blockIdx.x == 0) {
        int s = 0;
        for (int e = 0; e < N_EXP; e++) { offs[e] = s; s += counts[e]; }
    }
}

// GEMM1: h = relu(X_gathered @ W1[e]^T + b1[e])
__global__ __launch_bounds__(THREADS, 3) void gemm1_kernel(
        const unsigned short* __restrict__ xb, const unsigned short* __restrict__ w1b,
        const float* __restrict__ b1,
        const int* __restrict__ counts, const int* __restrict__ offs,
        const int* __restrict__ ltok,
        unsigned short* __restrict__ hb) {
    const int NTM = NTOK / BM;   // 64 (worst case)
    int b = blockIdx.x;
    int e = b & 7;               // expert -> XCD
    int idx = b >> 3;
    int nt = idx / NTM;          // W-panel major: co-resident blocks share nt
    int mt = idx % NTM;
    int cnt = counts[e];
    if (mt * BM >= cnt) return;

    __shared__ __align__(16) unsigned short As[BM * BK];   // 16 KB
    __shared__ __align__(16) unsigned short Bs[BN * BK];   // 16 KB

    int t = threadIdx.x;
    int lane = t & 63, w = t >> 6;     // 4 waves
    int wr = w >> 1, wc = w & 1;       // 2 x 2

    int srow = t >> 3;                       // 0..31
    int schunk = (t & 7) ^ (srow & 7);
    const unsigned short* aptr[4];
    const unsigned short* bptr[4];
    #pragma unroll
    for (int j = 0; j < 4; j++) {
        int rr = srow + j * 32;
        int slot = mt * BM + rr;
        int cs = slot < cnt ? slot : (cnt - 1);
        int tok = ltok[e * NTOK + cs];
        aptr[j] = xb + (size_t)tok * D_MODEL + schunk * 8;
        bptr[j] = w1b + ((size_t)e * D_FF + nt * BN + rr) * D_MODEL + schunk * 8;
    }
    char* As_b = (char*)As;
    char* Bs_b = (char*)Bs;

    int arow_base = wr * 64 + (lane & 15);
    int brow_base = wc * 64 + (lane & 15);
    int ch[2];
    #pragma unroll
    for (int ks = 0; ks < 2; ks++)
        ch[ks] = ((ks * 4 + (lane >> 4)) ^ (lane & 7)) << 4;

    f32x4 acc[4][4];
    #pragma unroll
    for (int m = 0; m < 4; m++)
        #pragma unroll
        for (int n = 0; n < 4; n++)
            acc[m][n] = (f32x4){0.f, 0.f, 0.f, 0.f};

    for (int k0 = 0; k0 < D_MODEL; k0 += BK) {
        #pragma unroll
        for (int j = 0; j < 4; j++) {
            gload_lds16(aptr[j] + k0, As_b + j * 4096 + t * 16);
            gload_lds16(bptr[j] + k0, Bs_b + j * 4096 + t * 16);
        }
        __syncthreads();
        bf16x8 af[2][4], bf[2][4];
        #pragma unroll
        for (int ks = 0; ks < 2; ks++) {
            #pragma unroll
            for (int m = 0; m < 4; m++)
                af[ks][m] = *(const bf16x8*)(As_b + (size_t)(arow_base + m * 16) * 128 + ch[ks]);
            #pragma unroll
            for (int n = 0; n < 4; n++)
                bf[ks][n] = *(const bf16x8*)(Bs_b + (size_t)(brow_base + n * 16) * 128 + ch[ks]);
        }
        #pragma unroll
        for (int ks = 0; ks < 2; ks++)
            #pragma unroll
            for (int m = 0; m < 4; m++)
                #pragma unroll
                for (int n = 0; n < 4; n++)
                    acc[m][n] = __builtin_amdgcn_mfma_f32_16x16x32_bf16(af[ks][m], bf[ks][n], acc[m][n], 0, 0, 0);
        __syncthreads();
    }

    // ---- epilogue: relu+bias, per-wave LDS repack, coalesced ushort8 stores
    int hbase = offs[e];
    float biasv[4];
    #pragma unroll
    for (int n = 0; n < 4; ++n)
        biasv[n] = b1[e * D_FF + nt * BN + wc * 64 + n * 16 + (lane & 15)];
    unsigned short* Hs = (unsigned short*)(As_b) + w * 1216;
    #pragma unroll
    for (int m = 0; m < 4; ++m) {
        #pragma unroll
        for (int n = 0; n < 4; ++n) {
            #pragma unroll
            for (int rq = 0; rq < 4; ++rq) {
                int lr = (lane >> 4) * 4 + rq;      // 0..15
                int lc = n * 16 + (lane & 15);      // 0..63
                float v = fmaxf(acc[m][n][rq] + biasv[n], 0.f);
                Hs[lr * 72 + lc] = f2bf(v);
            }
        }
        #pragma unroll
        for (int half = 0; half < 2; ++half) {
            int lr = half * 8 + (lane >> 3);        // 0..15
            u16x8 vv = *(const u16x8*)(Hs + lr * 72 + (lane & 7) * 8);
            int s = mt * BM + wr * 64 + m * 16 + lr;
            if (s < cnt) {
                *(u16x8*)(hb + (size_t)(hbase + s) * D_FF + nt * BN + wc * 64 + (lane & 7) * 8) = vv;
            }
        }
    }
}

// GEMM2: y = h @ W2[e]^T + b2[e]; weighted atomic scatter to out
__global__ __launch_bounds__(THREADS, 3) void gemm2_kernel(
        const unsigned short* __restrict__ hb, const unsigned short* __restrict__ w2b,
        const float* __restrict__ b2,
        const int* __restrict__ counts, const int* __restrict__ offs,
        const int* __restrict__ ltok, const float* __restrict__ lw,
        float* __restrict__ out) {
    const int NTM = NTOK / BM;     // 64
    int b = blockIdx.x;
    int e = b & 7;
    int idx = b >> 3;
    int nt = idx / NTM;
    int mt = idx % NTM;
    int cnt = counts[e];
    if (mt * BM >= cnt) return;
    int hbase = offs[e];

    __shared__ __align__(16) unsigned short As[BM * BK];
    __shared__ __align__(16) unsigned short Bs[BN * BK];

    int t = threadIdx.x;
    int lane = t & 63, w = t >> 6;
    int wr = w >> 1, wc = w & 1;

    int srow = t >> 3;
    int schunk = (t & 7) ^ (srow & 7);
    const unsigned short* aptr[4];
    const unsigned short* bptr[4];
    #pragma unroll
    for (int j = 0; j < 4; j++) {
        int rr = srow + j * 32;
        int slot = mt * BM + rr;
        int cs = slot < cnt ? slot : (cnt - 1);
        aptr[j] = hb + (size_t)(hbase + cs) * D_FF + schunk * 8;
        bptr[j] = w2b + ((size_t)e * D_MODEL + nt * BN + rr) * D_FF + schunk * 8;
    }
    char* As_b = (char*)As;
    char* Bs_b = (char*)Bs;

    int arow_base = wr * 64 + (lane & 15);
    int brow_base = wc * 64 + (lane & 15);
    int ch[2];
    #pragma unroll
    for (int ks = 0; ks < 2; ks++)
        ch[ks] = ((ks * 4 + (lane >> 4)) ^ (lane & 7)) << 4;

    f32x4 acc[4][4];
    #pragma unroll
    for (int m = 0; m < 4; m++)
        #pragma unroll
        for (int n = 0; n < 4; n++)
            acc[m][n] = (f32x4){0.f, 0.f, 0.f, 0.f};

    for (int k0 = 0; k0 < D_FF; k0 += BK) {
        #pragma unroll
        for (int j = 0; j < 4; j++) {
            gload_lds16(aptr[j] + k0, As_b + j * 4096 + t * 16);
            gload_lds16(bptr[j] + k0, Bs_b + j * 4096 + t * 16);
        }
        __syncthreads();
        bf16x8 af[2][4], bf[2][4];
        #pragma unroll
        for (int ks = 0; ks < 2; ks++) {
            #pragma unroll
            for (int m = 0; m < 4; m++)
                af[ks][m] = *(const bf16x8*)(As_b + (size_t)(arow_base + m * 16) * 128 + ch[ks]);
            #pragma unroll
            for (int n = 0; n < 4; n++)
                bf[ks][n] = *(const bf16x8*)(Bs_b + (size_t)(brow_base + n * 16) * 128 + ch[ks]);
        }
        #pragma unroll
        for (int ks = 0; ks < 2; ks++)
            #pragma unroll
            for (int m = 0; m < 4; m++)
                #pragma unroll
                for (int n = 0; n < 4; n++)
                    acc[m][n] = __builtin_amdgcn_mfma_f32_16x16x32_bf16(af[ks][m], bf[ks][n], acc[m][n], 0, 0, 0);
        __syncthreads();
    }

    int lbase = e * NTOK;
    float biasv[4];
    #pragma unroll
    for (int n = 0; n < 4; ++n)
        biasv[n] = b2[e * D_MODEL + nt * BN + wc * 64 + n * 16 + (lane & 15)];
    #pragma unroll
    for (int m = 0; m < 4; ++m) {
        int s0 = mt * BM + wr * 64 + m * 16 + (lane >> 4) * 4;
        #pragma unroll
        for (int rq = 0; rq < 4; ++rq) {
            int s = s0 + rq;
            if (s >= cnt) continue;
            int tok = ltok[lbase + s];
            float wgt = lw[lbase + s];
            float* orow = out + (size_t)tok * D_MODEL + nt * BN + wc * 64 + (lane & 15);
            #pragma unroll
            for (int n = 0; n < 4; ++n)
                atomicAdd(orow + n * 16, wgt * (acc[m][n][rq] + biasv[n]));
        }
    }
}

extern "C" void kernel_launch(void* const* d_in, const int* in_sizes, int n_in,
                              void* d_out, int out_size, void* d_ws, size_t ws_size,
                              hipStream_t stream) {
    const float* x  = (const float*)d_in[0];
    const float* gw = (const float*)d_in[1];
    const float* W1 = (const float*)d_in[2];
    const float* b1 = (const float*)d_in[3];
    const float* W2 = (const float*)d_in[4];
    const float* b2 = (const float*)d_in[5];
    float* out = (float*)d_out;

    char* ws = (char*)d_ws;
    size_t off = 0;
    auto alloc = [&](size_t bytes) -> char* {
        char* p = ws + off;
        off += (bytes + 255) & ~(size_t)255;
        return p;
    };
    unsigned short* xb  = (unsigned short*)alloc((size_t)NTOK * D_MODEL * 2);
    unsigned short* w1b = (unsigned short*)alloc((size_t)N_EXP * D_FF * D_MODEL * 2);
    unsigned short* w2b = (unsigned short*)alloc((size_t)N_EXP * D_MODEL * D_FF * 2);
    unsigned short* hb  = (unsigned short*)alloc((size_t)NASSIGN * D_FF * 2);
    int*   counts = (int*)alloc(256);
    int*   offs   = (int*)alloc(256);
    int*   ltok   = (int*)alloc((size_t)N_EXP * NTOK * 4);
    float* lw     = (float*)alloc((size_t)N_EXP * NTOK * 4);

    hipMemsetAsync(counts, 0, 256, stream);
    fused_pre_kernel<<<4096, 256, 0, stream>>>(
        x, gw, counts, ltok, lw, xb, out,
        W1, w1b, (long)N_EXP * D_FF * D_MODEL, W2, w2b, (long)N_EXP * D_MODEL * D_FF);
    scan_kernel<<<1, 64, 0, stream>>>(counts, offs);
    gemm1_kernel<<<N_EXP * (NTOK / BM) * (D_FF / BN), THREADS, 0, stream>>>(
        xb, w1b, b1, counts, offs, ltok, hb);
    gemm2_kernel<<<N_EXP * (NTOK / BM) * (D_MODEL / BN), THREADS, 0, stream>>>(
        hb, w2b, b2, counts, offs, ltok, lw, out);
}

// Round 18
// 599.222 us; speedup vs baseline: 1.5218x; 1.0921x over previous
//
#include <hip/hip_runtime.h>
#include <hip/hip_bf16.h>
#include <stdint.h>

#define D_MODEL 1024
#define D_FF    4096
#define N_EXP   8
#define TOPK    2
#define NTOK    8192
#define NASSIGN (NTOK*TOPK)

#define BM 128
#define BN 128
#define BK 64
#define THREADS 256

typedef __bf16 bf16_t;
typedef __attribute__((ext_vector_type(8))) bf16_t bf16x8;
typedef __attribute__((ext_vector_type(4))) float f32x4;
typedef __attribute__((ext_vector_type(4))) float f32v4;
typedef __attribute__((ext_vector_type(8))) unsigned short u16x8;
typedef __attribute__((ext_vector_type(4))) unsigned short u16x4;

__device__ __forceinline__ unsigned short f2bf(float f) {
    bf16_t b = (bf16_t)f;
    return __builtin_bit_cast(unsigned short, b);
}

__device__ __forceinline__ void gload_lds16(const void* g, void* l) {
    __builtin_amdgcn_global_load_lds(
        (const __attribute__((address_space(1))) void*)g,
        (__attribute__((address_space(3))) void*)l, 16, 0, 0);
}

// =====================================================================
// r18: kill the router's 16K same-line cross-XCD atomics (r17 counters:
// fused_pre 280us @ VALU 5% / HBM 15% / occ 74% = serialized-resource
// signature). Router now writes per-token records (plain stores);
// build_lists (1 block, 8 waves, wave e owns expert e) constructs
// ltok/lw/counts/offs via ballot+popcount prefix — deterministic,
// ~5-10us, absorbs scan + counts-memset. cvt: nontemporal streams.
// GEMMs byte-identical to r16/r17 fingerprint.
// =====================================================================
__global__ __launch_bounds__(256) void fused_pre_kernel(
        const float* __restrict__ x, const float* __restrict__ gw,
        int* __restrict__ recE, float* __restrict__ recW,
        unsigned short* __restrict__ xb, float* __restrict__ out,
        const float* __restrict__ W1, unsigned short* __restrict__ o1, long n1,
        const float* __restrict__ W2, unsigned short* __restrict__ o2, long n2) {
    int blk = blockIdx.x;
    if (blk < 2048) {
        // ---------------- router: wave w -> token blk*4+w ----------------
        int w = threadIdx.x >> 6;
        int lane = threadIdx.x & 63;
        int n = blk * 4 + w;
        const float* xr = x + (size_t)n * D_MODEL;
        unsigned short* xbr = xb + (size_t)n * D_MODEL;
        float4 z = make_float4(0.f, 0.f, 0.f, 0.f);
        float4* orow4 = (float4*)(out + (size_t)n * D_MODEL);
        #pragma unroll
        for (int i = 0; i < 4; i++) orow4[lane + i * 64] = z;

        float acc[N_EXP];
        #pragma unroll
        for (int e = 0; e < N_EXP; e++) acc[e] = 0.f;
        #pragma unroll
        for (int i = 0; i < 4; i++) {
            int j = lane + i * 64;                  // float4 index
            float4 v = ((const float4*)xr)[j];
            ushort4 o;
            o.x = f2bf(v.x); o.y = f2bf(v.y); o.z = f2bf(v.z); o.w = f2bf(v.w);
            ((ushort4*)xbr)[j] = o;
            int d = j * 4;
            #pragma unroll
            for (int e = 0; e < N_EXP; e++) {
                const float* g = gw + e * D_MODEL + d;
                acc[e] += v.x * g[0] + v.y * g[1] + v.z * g[2] + v.w * g[3];
            }
        }
        #pragma unroll
        for (int e = 0; e < N_EXP; e++) {
            #pragma unroll
            for (int off = 32; off > 0; off >>= 1)
                acc[e] += __shfl_down(acc[e], off);
        }
        if (lane == 0) {
            float mx = acc[0];
            #pragma unroll
            for (int e = 1; e < N_EXP; e++) mx = fmaxf(mx, acc[e]);
            float p[N_EXP];
            float s = 0.f;
            #pragma unroll
            for (int e = 0; e < N_EXP; e++) { p[e] = expf(acc[e] - mx); s += p[e]; }
            float inv = 1.f / s;
            #pragma unroll
            for (int e = 0; e < N_EXP; e++) p[e] *= inv;
            int i0 = 0;
            #pragma unroll
            for (int e = 1; e < N_EXP; e++) if (p[e] > p[i0]) i0 = e;
            int i1 = (i0 == 0) ? 1 : 0;
            #pragma unroll
            for (int e = 0; e < N_EXP; e++) if (e != i0 && p[e] > p[i1]) i1 = e;
            float s2 = p[i0] + p[i1] + 1e-9f;
            // plain stores — NO atomics
            recE[2 * n]     = i0;  recW[2 * n]     = p[i0] / s2;
            recE[2 * n + 1] = i1;  recW[2 * n + 1] = p[i1] / s2;
        }
    } else {
        // ---------- weight cvt: fp32 -> bf16, nontemporal streams ----------
        long stride = 2048L * 256;
        long q1 = n1 / 8, q2 = n2 / 8;
        for (long i = (long)(blk - 2048) * 256 + threadIdx.x; i < q1 + q2; i += stride) {
            const f32v4* src; u16x4* dst; long k;
            if (i < q1) { src = (const f32v4*)W1; dst = (u16x4*)o1; k = i; }
            else        { src = (const f32v4*)W2; dst = (u16x4*)o2; k = i - q1; }
            f32v4 v0 = __builtin_nontemporal_load(src + 2 * k);
            f32v4 v1 = __builtin_nontemporal_load(src + 2 * k + 1);
            u16x4 a, b;
            a.x = f2bf(v0.x); a.y = f2bf(v0.y); a.z = f2bf(v0.z); a.w = f2bf(v0.w);
            b.x = f2bf(v1.x); b.y = f2bf(v1.y); b.z = f2bf(v1.z); b.w = f2bf(v1.w);
            __builtin_nontemporal_store(a, dst + 2 * k);
            __builtin_nontemporal_store(b, dst + 2 * k + 1);
        }
    }
}

// ---------------- build per-expert lists (atomic-free, deterministic) ----------------
// One block, 8 waves. Wave e scans all NASSIGN records; ballot+popcount
// gives stable positions. Also writes counts and the exclusive scan.
__global__ __launch_bounds__(512) void build_lists_kernel(
        const int* __restrict__ recE, const float* __restrict__ recW,
        int* __restrict__ counts, int* __restrict__ offs,
        int* __restrict__ ltok, float* __restrict__ lw) {
    int we = threadIdx.x >> 6;        // expert this wave owns
    int lane = threadIdx.x & 63;
    int base = 0;
    for (int j0 = 0; j0 < NASSIGN; j0 += 64) {
        int e = recE[j0 + lane];
        float wt = recW[j0 + lane];
        unsigned long long m = __ballot(e == we);
        if (e == we) {
            int pos = base + __builtin_popcountll(m & ((1ull << lane) - 1));
            ltok[we * NTOK + pos] = (j0 + lane) >> 1;   // token index
            lw[we * NTOK + pos] = wt;
        }
        base += __builtin_popcountll(m);
    }
    if (lane == 0) counts[we] = base;
    __syncthreads();
    if (threadIdx.x == 0) {
        int s = 0;
        for (int e = 0; e < N_EXP; e++) { offs[e] = s; s += counts[e]; }
    }
}

// GEMM1: h = relu(X_gathered @ W1[e]^T + b1[e])
__global__ __launch_bounds__(THREADS, 3) void gemm1_kernel(
        const unsigned short* __restrict__ xb, const unsigned short* __restrict__ w1b,
        const float* __restrict__ b1,
        const int* __restrict__ counts, const int* __restrict__ offs,
        const int* __restrict__ ltok,
        unsigned short* __restrict__ hb) {
    const int NTM = NTOK / BM;   // 64 (worst case)
    int b = blockIdx.x;
    int e = b & 7;               // expert -> XCD
    int idx = b >> 3;
    int nt = idx / NTM;          // W-panel major: co-resident blocks share nt
    int mt = idx % NTM;
    int cnt = counts[e];
    if (mt * BM >= cnt) return;

    __shared__ __align__(16) unsigned short As[BM * BK];   // 16 KB
    __shared__ __align__(16) unsigned short Bs[BN * BK];   // 16 KB

    int t = threadIdx.x;
    int lane = t & 63, w = t >> 6;     // 4 waves
    int wr = w >> 1, wc = w & 1;       // 2 x 2

    int srow = t >> 3;                       // 0..31
    int schunk = (t & 7) ^ (srow & 7);
    const unsigned short* aptr[4];
    const unsigned short* bptr[4];
    #pragma unroll
    for (int j = 0; j < 4; j++) {
        int rr = srow + j * 32;
        int slot = mt * BM + rr;
        int cs = slot < cnt ? slot : (cnt - 1);
        int tok = ltok[e * NTOK + cs];
        aptr[j] = xb + (size_t)tok * D_MODEL + schunk * 8;
        bptr[j] = w1b + ((size_t)e * D_FF + nt * BN + rr) * D_MODEL + schunk * 8;
    }
    char* As_b = (char*)As;
    char* Bs_b = (char*)Bs;

    int arow_base = wr * 64 + (lane & 15);
    int brow_base = wc * 64 + (lane & 15);
    int ch[2];
    #pragma unroll
    for (int ks = 0; ks < 2; ks++)
        ch[ks] = ((ks * 4 + (lane >> 4)) ^ (lane & 7)) << 4;

    f32x4 acc[4][4];
    #pragma unroll
    for (int m = 0; m < 4; m++)
        #pragma unroll
        for (int n = 0; n < 4; n++)
            acc[m][n] = (f32x4){0.f, 0.f, 0.f, 0.f};

    for (int k0 = 0; k0 < D_MODEL; k0 += BK) {
        #pragma unroll
        for (int j = 0; j < 4; j++) {
            gload_lds16(aptr[j] + k0, As_b + j * 4096 + t * 16);
            gload_lds16(bptr[j] + k0, Bs_b + j * 4096 + t * 16);
        }
        __syncthreads();
        bf16x8 af[2][4], bf[2][4];
        #pragma unroll
        for (int ks = 0; ks < 2; ks++) {
            #pragma unroll
            for (int m = 0; m < 4; m++)
                af[ks][m] = *(const bf16x8*)(As_b + (size_t)(arow_base + m * 16) * 128 + ch[ks]);
            #pragma unroll
            for (int n = 0; n < 4; n++)
                bf[ks][n] = *(const bf16x8*)(Bs_b + (size_t)(brow_base + n * 16) * 128 + ch[ks]);
        }
        #pragma unroll
        for (int ks = 0; ks < 2; ks++)
            #pragma unroll
            for (int m = 0; m < 4; m++)
                #pragma unroll
                for (int n = 0; n < 4; n++)
                    acc[m][n] = __builtin_amdgcn_mfma_f32_16x16x32_bf16(af[ks][m], bf[ks][n], acc[m][n], 0, 0, 0);
        __syncthreads();
    }

    // ---- epilogue: relu+bias, per-wave LDS repack, coalesced ushort8 stores
    int hbase = offs[e];
    float biasv[4];
    #pragma unroll
    for (int n = 0; n < 4; ++n)
        biasv[n] = b1[e * D_FF + nt * BN + wc * 64 + n * 16 + (lane & 15)];
    unsigned short* Hs = (unsigned short*)(As_b) + w * 1216;
    #pragma unroll
    for (int m = 0; m < 4; ++m) {
        #pragma unroll
        for (int n = 0; n < 4; ++n) {
            #pragma unroll
            for (int rq = 0; rq < 4; ++rq) {
                int lr = (lane >> 4) * 4 + rq;      // 0..15
                int lc = n * 16 + (lane & 15);      // 0..63
                float v = fmaxf(acc[m][n][rq] + biasv[n], 0.f);
                Hs[lr * 72 + lc] = f2bf(v);
            }
        }
        #pragma unroll
        for (int half = 0; half < 2; ++half) {
            int lr = half * 8 + (lane >> 3);        // 0..15
            u16x8 vv = *(const u16x8*)(Hs + lr * 72 + (lane & 7) * 8);
            int s = mt * BM + wr * 64 + m * 16 + lr;
            if (s < cnt) {
                *(u16x8*)(hb + (size_t)(hbase + s) * D_FF + nt * BN + wc * 64 + (lane & 7) * 8) = vv;
            }
        }
    }
}

// GEMM2: y = h @ W2[e]^T + b2[e]; weighted atomic scatter to out
__global__ __launch_bounds__(THREADS, 3) void gemm2_kernel(
        const unsigned short* __restrict__ hb, const unsigned short* __restrict__ w2b,
        const float* __restrict__ b2,
        const int* __restrict__ counts, const int* __restrict__ offs,
        const int* __restrict__ ltok, const float* __restrict__ lw,
        float* __restrict__ out) {
    const int NTM = NTOK / BM;     // 64
    int b = blockIdx.x;
    int e = b & 7;
    int idx = b >> 3;
    int nt = idx / NTM;
    int mt = idx % NTM;
    int cnt = counts[e];
    if (mt * BM >= cnt) return;
    int hbase = offs[e];

    __shared__ __align__(16) unsigned short As[BM * BK];
    __shared__ __align__(16) unsigned short Bs[BN * BK];

    int t = threadIdx.x;
    int lane = t & 63, w = t >> 6;
    int wr = w >> 1, wc = w & 1;

    int srow = t >> 3;
    int schunk = (t & 7) ^ (srow & 7);
    const unsigned short* aptr[4];
    const unsigned short* bptr[4];
    #pragma unroll
    for (int j = 0; j < 4; j++) {
        int rr = srow + j * 32;
        int slot = mt * BM + rr;
        int cs = slot < cnt ? slot : (cnt - 1);
        aptr[j] = hb + (size_t)(hbase + cs) * D_FF + schunk * 8;
        bptr[j] = w2b + ((size_t)e * D_MODEL + nt * BN + rr) * D_FF + schunk * 8;
    }
    char* As_b = (char*)As;
    char* Bs_b = (char*)Bs;

    int arow_base = wr * 64 + (lane & 15);
    int brow_base = wc * 64 + (lane & 15);
    int ch[2];
    #pragma unroll
    for (int ks = 0; ks < 2; ks++)
        ch[ks] = ((ks * 4 + (lane >> 4)) ^ (lane & 7)) << 4;

    f32x4 acc[4][4];
    #pragma unroll
    for (int m = 0; m < 4; m++)
        #pragma unroll
        for (int n = 0; n < 4; n++)
            acc[m][n] = (f32x4){0.f, 0.f, 0.f, 0.f};

    for (int k0 = 0; k0 < D_FF; k0 += BK) {
        #pragma unroll
        for (int j = 0; j < 4; j++) {
            gload_lds16(aptr[j] + k0, As_b + j * 4096 + t * 16);
            gload_lds16(bptr[j] + k0, Bs_b + j * 4096 + t * 16);
        }
        __syncthreads();
        bf16x8 af[2][4], bf[2][4];
        #pragma unroll
        for (int ks = 0; ks < 2; ks++) {
            #pragma unroll
            for (int m = 0; m < 4; m++)
                af[ks][m] = *(const bf16x8*)(As_b + (size_t)(arow_base + m * 16) * 128 + ch[ks]);
            #pragma unroll
            for (int n = 0; n < 4; n++)
                bf[ks][n] = *(const bf16x8*)(Bs_b + (size_t)(brow_base + n * 16) * 128 + ch[ks]);
        }
        #pragma unroll
        for (int ks = 0; ks < 2; ks++)
            #pragma unroll
            for (int m = 0; m < 4; m++)
                #pragma unroll
                for (int n = 0; n < 4; n++)
                    acc[m][n] = __builtin_amdgcn_mfma_f32_16x16x32_bf16(af[ks][m], bf[ks][n], acc[m][n], 0, 0, 0);
        __syncthreads();
    }

    int lbase = e * NTOK;
    float biasv[4];
    #pragma unroll
    for (int n = 0; n < 4; ++n)
        biasv[n] = b2[e * D_MODEL + nt * BN + wc * 64 + n * 16 + (lane & 15)];
    #pragma unroll
    for (int m = 0; m < 4; ++m) {
        int s0 = mt * BM + wr * 64 + m * 16 + (lane >> 4) * 4;
        #pragma unroll
        for (int rq = 0; rq < 4; ++rq) {
            int s = s0 + rq;
            if (s >= cnt) continue;
            int tok = ltok[lbase + s];
            float wgt = lw[lbase + s];
            float* orow = out + (size_t)tok * D_MODEL + nt * BN + wc * 64 + (lane & 15);
            #pragma unroll
            for (int n = 0; n < 4; ++n)
                atomicAdd(orow + n * 16, wgt * (acc[m][n][rq] + biasv[n]));
        }
    }
}

extern "C" void kernel_launch(void* const* d_in, const int* in_sizes, int n_in,
                              void* d_out, int out_size, void* d_ws, size_t ws_size,
                              hipStream_t stream) {
    const float* x  = (const float*)d_in[0];
    const float* gw = (const float*)d_in[1];
    const float* W1 = (const float*)d_in[2];
    const float* b1 = (const float*)d_in[3];
    const float* W2 = (const float*)d_in[4];
    const float* b2 = (const float*)d_in[5];
    float* out = (float*)d_out;

    char* ws = (char*)d_ws;
    size_t off = 0;
    auto alloc = [&](size_t bytes) -> char* {
        char* p = ws + off;
        off += (bytes + 255) & ~(size_t)255;
        return p;
    };
    unsigned short* xb  = (unsigned short*)alloc((size_t)NTOK * D_MODEL * 2);
    unsigned short* w1b = (unsigned short*)alloc((size_t)N_EXP * D_FF * D_MODEL * 2);
    unsigned short* w2b = (unsigned short*)alloc((size_t)N_EXP * D_MODEL * D_FF * 2);
    unsigned short* hb  = (unsigned short*)alloc((size_t)NASSIGN * D_FF * 2);
    int*   counts = (int*)alloc(256);
    int*   offs   = (int*)alloc(256);
    int*   ltok   = (int*)alloc((size_t)N_EXP * NTOK * 4);
    float* lw     = (float*)alloc((size_t)N_EXP * NTOK * 4);
    int*   recE   = (int*)alloc((size_t)NASSIGN * 4);
    float* recW   = (float*)alloc((size_t)NASSIGN * 4);

    fused_pre_kernel<<<4096, 256, 0, stream>>>(
        x, gw, recE, recW, xb, out,
        W1, w1b, (long)N_EXP * D_FF * D_MODEL, W2, w2b, (long)N_EXP * D_MODEL * D_FF);
    build_lists_kernel<<<1, 512, 0, stream>>>(recE, recW, counts, offs, ltok, lw);
    gemm1_kernel<<<N_EXP * (NTOK / BM) * (D_FF / BN), THREADS, 0, stream>>>(
        xb, w1b, b1, counts, offs, ltok, hb);
    gemm2_kernel<<<N_EXP * (NTOK / BM) * (D_MODEL / BN), THREADS, 0, stream>>>(
        hb, w2b, b2, counts, offs, ltok, lw, out);
}

// Round 19
// 590.533 us; speedup vs baseline: 1.5442x; 1.0147x over previous
//
#include <hip/hip_runtime.h>
#include <hip/hip_bf16.h>
#include <stdint.h>

#define D_MODEL 1024
#define D_FF    4096
#define N_EXP   8
#define TOPK    2
#define NTOK    8192
#define NASSIGN (NTOK*TOPK)

#define BM 128
#define BN 128
#define BK 64
#define THREADS 256
#define G1_BLOCKS (N_EXP * (NTOK / BM) * (D_FF / BN))   // 16384
#define CVT_BLOCKS 2048

typedef __bf16 bf16_t;
typedef __attribute__((ext_vector_type(8))) bf16_t bf16x8;
typedef __attribute__((ext_vector_type(4))) float f32x4;
typedef __attribute__((ext_vector_type(4))) float f32v4;
typedef __attribute__((ext_vector_type(8))) unsigned short u16x8;
typedef __attribute__((ext_vector_type(4))) unsigned short u16x4;

__device__ __forceinline__ unsigned short f2bf(float f) {
    bf16_t b = (bf16_t)f;
    return __builtin_bit_cast(unsigned short, b);
}

__device__ __forceinline__ void gload_lds16(const void* g, void* l) {
    __builtin_amdgcn_global_load_lds(
        (const __attribute__((address_space(1))) void*)g,
        (__attribute__((address_space(3))) void*)l, 16, 0, 0);
}

__device__ __forceinline__ void cvt_stream(const float* __restrict__ W,
                                           unsigned short* __restrict__ o,
                                           long n, long blk0) {
    long stride = (long)CVT_BLOCKS * 256;
    long q = n / 8;
    for (long i = blk0 * 256 + threadIdx.x; i < q; i += stride) {
        const f32v4* src = (const f32v4*)W;
        u16x4* dst = (u16x4*)o;
        f32v4 v0 = __builtin_nontemporal_load(src + 2 * i);
        f32v4 v1 = __builtin_nontemporal_load(src + 2 * i + 1);
        u16x4 a, b;
        a.x = f2bf(v0.x); a.y = f2bf(v0.y); a.z = f2bf(v0.z); a.w = f2bf(v0.w);
        b.x = f2bf(v1.x); b.y = f2bf(v1.y); b.z = f2bf(v1.z); b.w = f2bf(v1.w);
        __builtin_nontemporal_store(a, dst + 2 * i);
        __builtin_nontemporal_store(b, dst + 2 * i + 1);
    }
}

// =====================================================================
// r19 = r18 (atomic-free router, 599us) + W2-cvt PIPELINED UNDER GEMM1:
// gemm1 runs at ~12% HBM, so the 201MB W2 stream hides under its
// compute (extra blocks >= G1_BLOCKS; gemm1 block indices unchanged ->
// XCD/panel mapping byte-identical). fused_pre keeps router + W1 only.
// =====================================================================
__global__ __launch_bounds__(256) void fused_pre_kernel(
        const float* __restrict__ x, const float* __restrict__ gw,
        int* __restrict__ recE, float* __restrict__ recW,
        unsigned short* __restrict__ xb, float* __restrict__ out,
        const float* __restrict__ W1, unsigned short* __restrict__ o1, long n1) {
    int blk = blockIdx.x;
    if (blk < 2048) {
        // ---------------- router: wave w -> token blk*4+w ----------------
        int w = threadIdx.x >> 6;
        int lane = threadIdx.x & 63;
        int n = blk * 4 + w;
        const float* xr = x + (size_t)n * D_MODEL;
        unsigned short* xbr = xb + (size_t)n * D_MODEL;
        float4 z = make_float4(0.f, 0.f, 0.f, 0.f);
        float4* orow4 = (float4*)(out + (size_t)n * D_MODEL);
        #pragma unroll
        for (int i = 0; i < 4; i++) orow4[lane + i * 64] = z;

        float acc[N_EXP];
        #pragma unroll
        for (int e = 0; e < N_EXP; e++) acc[e] = 0.f;
        #pragma unroll
        for (int i = 0; i < 4; i++) {
            int j = lane + i * 64;                  // float4 index
            float4 v = ((const float4*)xr)[j];
            ushort4 o;
            o.x = f2bf(v.x); o.y = f2bf(v.y); o.z = f2bf(v.z); o.w = f2bf(v.w);
            ((ushort4*)xbr)[j] = o;
            int d = j * 4;
            #pragma unroll
            for (int e = 0; e < N_EXP; e++) {
                const float* g = gw + e * D_MODEL + d;
                acc[e] += v.x * g[0] + v.y * g[1] + v.z * g[2] + v.w * g[3];
            }
        }
        #pragma unroll
        for (int e = 0; e < N_EXP; e++) {
            #pragma unroll
            for (int off = 32; off > 0; off >>= 1)
                acc[e] += __shfl_down(acc[e], off);
        }
        if (lane == 0) {
            float mx = acc[0];
            #pragma unroll
            for (int e = 1; e < N_EXP; e++) mx = fmaxf(mx, acc[e]);
            float p[N_EXP];
            float s = 0.f;
            #pragma unroll
            for (int e = 0; e < N_EXP; e++) { p[e] = expf(acc[e] - mx); s += p[e]; }
            float inv = 1.f / s;
            #pragma unroll
            for (int e = 0; e < N_EXP; e++) p[e] *= inv;
            int i0 = 0;
            #pragma unroll
            for (int e = 1; e < N_EXP; e++) if (p[e] > p[i0]) i0 = e;
            int i1 = (i0 == 0) ? 1 : 0;
            #pragma unroll
            for (int e = 0; e < N_EXP; e++) if (e != i0 && p[e] > p[i1]) i1 = e;
            float s2 = p[i0] + p[i1] + 1e-9f;
            recE[2 * n]     = i0;  recW[2 * n]     = p[i0] / s2;
            recE[2 * n + 1] = i1;  recW[2 * n + 1] = p[i1] / s2;
        }
    } else {
        cvt_stream(W1, o1, n1, blk - 2048);
    }
}

// ---------------- build per-expert lists (atomic-free, deterministic) ----------------
__global__ __launch_bounds__(512) void build_lists_kernel(
        const int* __restrict__ recE, const float* __restrict__ recW,
        int* __restrict__ counts, int* __restrict__ offs,
        int* __restrict__ ltok, float* __restrict__ lw) {
    int we = threadIdx.x >> 6;        // expert this wave owns
    int lane = threadIdx.x & 63;
    int base = 0;
    for (int j0 = 0; j0 < NASSIGN; j0 += 64) {
        int e = recE[j0 + lane];
        float wt = recW[j0 + lane];
        unsigned long long m = __ballot(e == we);
        if (e == we) {
            int pos = base + __builtin_popcountll(m & ((1ull << lane) - 1));
            ltok[we * NTOK + pos] = (j0 + lane) >> 1;   // token index
            lw[we * NTOK + pos] = wt;
        }
        base += __builtin_popcountll(m);
    }
    if (lane == 0) counts[we] = base;
    __syncthreads();
    if (threadIdx.x == 0) {
        int s = 0;
        for (int e = 0; e < N_EXP; e++) { offs[e] = s; s += counts[e]; }
    }
}

// GEMM1: h = relu(X_gathered @ W1[e]^T + b1[e]); extra blocks cvt W2
__global__ __launch_bounds__(THREADS, 3) void gemm1_kernel(
        const unsigned short* __restrict__ xb, const unsigned short* __restrict__ w1b,
        const float* __restrict__ b1,
        const int* __restrict__ counts, const int* __restrict__ offs,
        const int* __restrict__ ltok,
        unsigned short* __restrict__ hb,
        const float* __restrict__ W2, unsigned short* __restrict__ o2, long n2) {
    const int NTM = NTOK / BM;   // 64 (worst case)
    int b = blockIdx.x;
    if (b >= G1_BLOCKS) {
        cvt_stream(W2, o2, n2, b - G1_BLOCKS);   // pipelined under gemm1
        return;
    }
    int e = b & 7;               // expert -> XCD
    int idx = b >> 3;
    int nt = idx / NTM;          // W-panel major: co-resident blocks share nt
    int mt = idx % NTM;
    int cnt = counts[e];
    if (mt * BM >= cnt) return;

    __shared__ __align__(16) unsigned short As[BM * BK];   // 16 KB
    __shared__ __align__(16) unsigned short Bs[BN * BK];   // 16 KB

    int t = threadIdx.x;
    int lane = t & 63, w = t >> 6;     // 4 waves
    int wr = w >> 1, wc = w & 1;       // 2 x 2

    int srow = t >> 3;                       // 0..31
    int schunk = (t & 7) ^ (srow & 7);
    const unsigned short* aptr[4];
    const unsigned short* bptr[4];
    #pragma unroll
    for (int j = 0; j < 4; j++) {
        int rr = srow + j * 32;
        int slot = mt * BM + rr;
        int cs = slot < cnt ? slot : (cnt - 1);
        int tok = ltok[e * NTOK + cs];
        aptr[j] = xb + (size_t)tok * D_MODEL + schunk * 8;
        bptr[j] = w1b + ((size_t)e * D_FF + nt * BN + rr) * D_MODEL + schunk * 8;
    }
    char* As_b = (char*)As;
    char* Bs_b = (char*)Bs;

    int arow_base = wr * 64 + (lane & 15);
    int brow_base = wc * 64 + (lane & 15);
    int ch[2];
    #pragma unroll
    for (int ks = 0; ks < 2; ks++)
        ch[ks] = ((ks * 4 + (lane >> 4)) ^ (lane & 7)) << 4;

    f32x4 acc[4][4];
    #pragma unroll
    for (int m = 0; m < 4; m++)
        #pragma unroll
        for (int n = 0; n < 4; n++)
            acc[m][n] = (f32x4){0.f, 0.f, 0.f, 0.f};

    for (int k0 = 0; k0 < D_MODEL; k0 += BK) {
        #pragma unroll
        for (int j = 0; j < 4; j++) {
            gload_lds16(aptr[j] + k0, As_b + j * 4096 + t * 16);
            gload_lds16(bptr[j] + k0, Bs_b + j * 4096 + t * 16);
        }
        __syncthreads();
        bf16x8 af[2][4], bf[2][4];
        #pragma unroll
        for (int ks = 0; ks < 2; ks++) {
            #pragma unroll
            for (int m = 0; m < 4; m++)
                af[ks][m] = *(const bf16x8*)(As_b + (size_t)(arow_base + m * 16) * 128 + ch[ks]);
            #pragma unroll
            for (int n = 0; n < 4; n++)
                bf[ks][n] = *(const bf16x8*)(Bs_b + (size_t)(brow_base + n * 16) * 128 + ch[ks]);
        }
        #pragma unroll
        for (int ks = 0; ks < 2; ks++)
            #pragma unroll
            for (int m = 0; m < 4; m++)
                #pragma unroll
                for (int n = 0; n < 4; n++)
                    acc[m][n] = __builtin_amdgcn_mfma_f32_16x16x32_bf16(af[ks][m], bf[ks][n], acc[m][n], 0, 0, 0);
        __syncthreads();
    }

    // ---- epilogue: relu+bias, per-wave LDS repack, coalesced ushort8 stores
    int hbase = offs[e];
    float biasv[4];
    #pragma unroll
    for (int n = 0; n < 4; ++n)
        biasv[n] = b1[e * D_FF + nt * BN + wc * 64 + n * 16 + (lane & 15)];
    unsigned short* Hs = (unsigned short*)(As_b) + w * 1216;
    #pragma unroll
    for (int m = 0; m < 4; ++m) {
        #pragma unroll
        for (int n = 0; n < 4; ++n) {
            #pragma unroll
            for (int rq = 0; rq < 4; ++rq) {
                int lr = (lane >> 4) * 4 + rq;      // 0..15
                int lc = n * 16 + (lane & 15);      // 0..63
                float v = fmaxf(acc[m][n][rq] + biasv[n], 0.f);
                Hs[lr * 72 + lc] = f2bf(v);
            }
        }
        #pragma unroll
        for (int half = 0; half < 2; ++half) {
            int lr = half * 8 + (lane >> 3);        // 0..15
            u16x8 vv = *(const u16x8*)(Hs + lr * 72 + (lane & 7) * 8);
            int s = mt * BM + wr * 64 + m * 16 + lr;
            if (s < cnt) {
                *(u16x8*)(hb + (size_t)(hbase + s) * D_FF + nt * BN + wc * 64 + (lane & 7) * 8) = vv;
            }
        }
    }
}

// GEMM2: y = h @ W2[e]^T + b2[e]; weighted atomic scatter to out
__global__ __launch_bounds__(THREADS, 3) void gemm2_kernel(
        const unsigned short* __restrict__ hb, const unsigned short* __restrict__ w2b,
        const float* __restrict__ b2,
        const int* __restrict__ counts, const int* __restrict__ offs,
        const int* __restrict__ ltok, const float* __restrict__ lw,
        float* __restrict__ out) {
    const int NTM = NTOK / BM;     // 64
    int b = blockIdx.x;
    int e = b & 7;
    int idx = b >> 3;
    int nt = idx / NTM;
    int mt = idx % NTM;
    int cnt = counts[e];
    if (mt * BM >= cnt) return;
    int hbase = offs[e];

    __shared__ __align__(16) unsigned short As[BM * BK];
    __shared__ __align__(16) unsigned short Bs[BN * BK];

    int t = threadIdx.x;
    int lane = t & 63, w = t >> 6;
    int wr = w >> 1, wc = w & 1;

    int srow = t >> 3;
    int schunk = (t & 7) ^ (srow & 7);
    const unsigned short* aptr[4];
    const unsigned short* bptr[4];
    #pragma unroll
    for (int j = 0; j < 4; j++) {
        int rr = srow + j * 32;
        int slot = mt * BM + rr;
        int cs = slot < cnt ? slot : (cnt - 1);
        aptr[j] = hb + (size_t)(hbase + cs) * D_FF + schunk * 8;
        bptr[j] = w2b + ((size_t)e * D_MODEL + nt * BN + rr) * D_FF + schunk * 8;
    }
    char* As_b = (char*)As;
    char* Bs_b = (char*)Bs;

    int arow_base = wr * 64 + (lane & 15);
    int brow_base = wc * 64 + (lane & 15);
    int ch[2];
    #pragma unroll
    for (int ks = 0; ks < 2; ks++)
        ch[ks] = ((ks * 4 + (lane >> 4)) ^ (lane & 7)) << 4;

    f32x4 acc[4][4];
    #pragma unroll
    for (int m = 0; m < 4; m++)
        #pragma unroll
        for (int n = 0; n < 4; n++)
            acc[m][n] = (f32x4){0.f, 0.f, 0.f, 0.f};

    for (int k0 = 0; k0 < D_FF; k0 += BK) {
        #pragma unroll
        for (int j = 0; j < 4; j++) {
            gload_lds16(aptr[j] + k0, As_b + j * 4096 + t * 16);
            gload_lds16(bptr[j] + k0, Bs_b + j * 4096 + t * 16);
        }
        __syncthreads();
        bf16x8 af[2][4], bf[2][4];
        #pragma unroll
        for (int ks = 0; ks < 2; ks++) {
            #pragma unroll
            for (int m = 0; m < 4; m++)
                af[ks][m] = *(const bf16x8*)(As_b + (size_t)(arow_base + m * 16) * 128 + ch[ks]);
            #pragma unroll
            for (int n = 0; n < 4; n++)
                bf[ks][n] = *(const bf16x8*)(Bs_b + (size_t)(brow_base + n * 16) * 128 + ch[ks]);
        }
        #pragma unroll
        for (int ks = 0; ks < 2; ks++)
            #pragma unroll
            for (int m = 0; m < 4; m++)
                #pragma unroll
                for (int n = 0; n < 4; n++)
                    acc[m][n] = __builtin_amdgcn_mfma_f32_16x16x32_bf16(af[ks][m], bf[ks][n], acc[m][n], 0, 0, 0);
        __syncthreads();
    }

    int lbase = e * NTOK;
    float biasv[4];
    #pragma unroll
    for (int n = 0; n < 4; ++n)
        biasv[n] = b2[e * D_MODEL + nt * BN + wc * 64 + n * 16 + (lane & 15)];
    #pragma unroll
    for (int m = 0; m < 4; ++m) {
        int s0 = mt * BM + wr * 64 + m * 16 + (lane >> 4) * 4;
        #pragma unroll
        for (int rq = 0; rq < 4; ++rq) {
            int s = s0 + rq;
            if (s >= cnt) continue;
            int tok = ltok[lbase + s];
            float wgt = lw[lbase + s];
            float* orow = out + (size_t)tok * D_MODEL + nt * BN + wc * 64 + (lane & 15);
            #pragma unroll
            for (int n = 0; n < 4; ++n)
                atomicAdd(orow + n * 16, wgt * (acc[m][n][rq] + biasv[n]));
        }
    }
}

extern "C" void kernel_launch(void* const* d_in, const int* in_sizes, int n_in,
                              void* d_out, int out_size, void* d_ws, size_t ws_size,
                              hipStream_t stream) {
    const float* x  = (const float*)d_in[0];
    const float* gw = (const float*)d_in[1];
    const float* W1 = (const float*)d_in[2];
    const float* b1 = (const float*)d_in[3];
    const float* W2 = (const float*)d_in[4];
    const float* b2 = (const float*)d_in[5];
    float* out = (float*)d_out;

    char* ws = (char*)d_ws;
    size_t off = 0;
    auto alloc = [&](size_t bytes) -> char* {
        char* p = ws + off;
        off += (bytes + 255) & ~(size_t)255;
        return p;
    };
    unsigned short* xb  = (unsigned short*)alloc((size_t)NTOK * D_MODEL * 2);
    unsigned short* w1b = (unsigned short*)alloc((size_t)N_EXP * D_FF * D_MODEL * 2);
    unsigned short* w2b = (unsigned short*)alloc((size_t)N_EXP * D_MODEL * D_FF * 2);
    unsigned short* hb  = (unsigned short*)alloc((size_t)NASSIGN * D_FF * 2);
    int*   counts = (int*)alloc(256);
    int*   offs   = (int*)alloc(256);
    int*   ltok   = (int*)alloc((size_t)N_EXP * NTOK * 4);
    float* lw     = (float*)alloc((size_t)N_EXP * NTOK * 4);
    int*   recE   = (int*)alloc((size_t)NASSIGN * 4);
    float* recW   = (float*)alloc((size_t)NASSIGN * 4);

    fused_pre_kernel<<<4096, 256, 0, stream>>>(
        x, gw, recE, recW, xb, out, W1, w1b, (long)N_EXP * D_FF * D_MODEL);
    build_lists_kernel<<<1, 512, 0, stream>>>(recE, recW, counts, offs, ltok, lw);
    gemm1_kernel<<<G1_BLOCKS + CVT_BLOCKS, THREADS, 0, stream>>>(
        xb, w1b, b1, counts, offs, ltok, hb,
        W2, w2b, (long)N_EXP * D_MODEL * D_FF);
    gemm2_kernel<<<N_EXP * (NTOK / BM) * (D_MODEL / BN), THREADS, 0, stream>>>(
        hb, w2b, b2, counts, offs, ltok, lw, out);
}